// Round 3
// baseline (1612.337 us; speedup 1.0000x reference)
//
#include <hip/hip_runtime.h>
#include <hip/hip_bf16.h>

#define DD 128

typedef __attribute__((ext_vector_type(8))) short short8;
typedef __attribute__((ext_vector_type(4))) float f32x4;
typedef __attribute__((ext_vector_type(8))) float f32x8;

__device__ __forceinline__ unsigned short f2bf(float f) {
    union { unsigned int u; float f; } c; c.f = f;
    unsigned int u = c.u;
    unsigned int r = (u + 0x7FFFu + ((u >> 16) & 1u)) >> 16;
    return (unsigned short)r;
}

// -------- scatter: pre[dst] += feats[src] (masked), deg[dst] += 1 --------
__global__ void scatter_kernel(const float* __restrict__ feats,
                               const int* __restrict__ src,
                               const int* __restrict__ dst,
                               const float* __restrict__ u,
                               float* __restrict__ pre,
                               float* __restrict__ deg,
                               int E)
{
    int tid  = blockIdx.x * blockDim.x + threadIdx.x;
    int lane = tid & 63;
    int wave = tid >> 6;
    int nw   = (gridDim.x * blockDim.x) >> 6;
    for (int e = wave; e < E; e += nw) {
        float uv = u[e];
        if (uv < 0.5f) {
            int s = src[e], d = dst[e];
            const float2 x = *(const float2*)(feats + (size_t)s * DD + 2 * lane);
            float* dp = pre + (size_t)d * DD + 2 * lane;
            unsafeAtomicAdd(dp,     x.x);
            unsafeAtomicAdd(dp + 1, x.y);
            if (lane == 0) unsafeAtomicAdd(deg + d, 1.0f);
        }
    }
}

// -------- table update: comb = X@Wself^T + bself + fmask*((pre/deg)@Wedge^T + (deg>0)*bedge)
//          LN -> +residual -> SELU -> column-mask select --------
__global__ __launch_bounds__(512)
void table_kernel(const float* __restrict__ feats,
                  const float* __restrict__ pre,
                  const float* __restrict__ deg,
                  const float* __restrict__ Wself,
                  const float* __restrict__ bself,
                  const float* __restrict__ Wedge,
                  const float* __restrict__ bedge,
                  const float* __restrict__ lnw,
                  const float* __restrict__ lnb,
                  const float* __restrict__ ufeat,
                  float* __restrict__ out,
                  int N)
{
    __shared__ float comb[32][132];

    const int tid  = threadIdx.x;
    const int wave = tid >> 6;
    const int lane = tid & 63;
    const int rowgroup = wave >> 2;   // 0/1 -> rows [0..15] / [16..31] of block tile
    const int cp   = wave & 3;        // col-tile pair: tiles 2cp, 2cp+1
    const int lj   = lane & 15;       // col (B) / row (A) within 16-tile
    const int lk   = lane >> 4;       // k subgroup (8 elems each)

    // ---- weight fragments (f32 -> bf16), loaded once; fmask folded into Wedge ----
    short8 wS[2][4], wE[2][4];
    for (int c = 0; c < 2; ++c) {
        int j = (cp * 2 + c) * 16 + lj;
        bool fm = ufeat[j] < 0.3f;
        for (int t = 0; t < 4; ++t) {
            int k0 = t * 32 + lk * 8;
            short8 ws, we;
            #pragma unroll
            for (int i = 0; i < 8; ++i) {
                ((unsigned short*)&ws)[i] = f2bf(Wself[j * DD + k0 + i]);
                ((unsigned short*)&we)[i] = fm ? f2bf(Wedge[j * DD + k0 + i]) : 0;
            }
            wS[c][t] = ws;
            wE[c][t] = we;
        }
    }

    const int iters = N / 32;
    for (int it = blockIdx.x; it < iters; it += gridDim.x) {
        int row0 = it * 32 + rowgroup * 16;
        int r = row0 + lj;                      // A-frag row for this lane
        float invd = 1.0f / fmaxf(deg[r], 1.0f);

        f32x4 acc0 = {0.f, 0.f, 0.f, 0.f};
        f32x4 acc1 = {0.f, 0.f, 0.f, 0.f};
        for (int t = 0; t < 4; ++t) {
            int k0 = t * 32 + lk * 8;
            const float* xp = feats + (size_t)r * DD + k0;
            const float* pp = pre   + (size_t)r * DD + k0;
            short8 xf, pf;
            #pragma unroll
            for (int i = 0; i < 8; ++i) {
                ((unsigned short*)&xf)[i] = f2bf(xp[i]);
                ((unsigned short*)&pf)[i] = f2bf(pp[i] * invd);
            }
            acc0 = __builtin_amdgcn_mfma_f32_16x16x32_bf16(xf, wS[0][t], acc0, 0, 0, 0);
            acc1 = __builtin_amdgcn_mfma_f32_16x16x32_bf16(xf, wS[1][t], acc1, 0, 0, 0);
            acc0 = __builtin_amdgcn_mfma_f32_16x16x32_bf16(pf, wE[0][t], acc0, 0, 0, 0);
            acc1 = __builtin_amdgcn_mfma_f32_16x16x32_bf16(pf, wE[1][t], acc1, 0, 0, 0);
        }

        // C/D layout: col = lane&15, row = (lane>>4)*4 + reg   [m89-verified]
        #pragma unroll
        for (int c = 0; c < 2; ++c) {
            f32x4 a = c ? acc1 : acc0;
            int col = (cp * 2 + c) * 16 + lj;
            #pragma unroll
            for (int q = 0; q < 4; ++q) {
                int rr = rowgroup * 16 + lk * 4 + q;
                comb[rr][col] = a[q];
            }
        }
        __syncthreads();

        // ---- LN + SELU epilogue: 16 threads per row ----
        {
            int rr   = tid >> 4;
            int slot = tid & 15;
            int grow = it * 32 + rr;
            float dg = deg[grow];
            float degpos = dg > 0.5f ? 1.0f : 0.0f;

            float v[8];
            float s = 0.f, s2 = 0.f;
            #pragma unroll
            for (int i = 0; i < 8; ++i) {
                int col = slot * 8 + i;
                float fm = ufeat[col] < 0.3f ? 1.0f : 0.0f;
                float val = comb[rr][col] + bself[col] + fm * degpos * bedge[col];
                v[i] = val; s += val; s2 += val * val;
            }
            #pragma unroll
            for (int m = 1; m < 16; m <<= 1) {
                s  += __shfl_xor(s,  m, 64);
                s2 += __shfl_xor(s2, m, 64);
            }
            float mu   = s * (1.0f / 128.0f);
            float var  = s2 * (1.0f / 128.0f) - mu * mu;
            float rstd = rsqrtf(var + 1e-5f);

            const float* frow = feats + (size_t)grow * DD + slot * 8;
            float ofrag[8];
            #pragma unroll
            for (int i = 0; i < 8; ++i) {
                int col = slot * 8 + i;
                bool fm = ufeat[col] < 0.3f;
                float ln = (v[i] - mu) * rstd * lnw[col] + lnb[col];
                float f  = frow[i];
                float x  = ln + f;
                float selu = x > 0.f ? 1.0507009873554805f * x
                                     : 1.0507009873554805f * 1.6732632423543772f * (expf(x) - 1.0f);
                ofrag[i] = fm ? selu : f;
            }
            *(f32x8*)(out + (size_t)grow * DD + slot * 8) = *(f32x8*)ofrag;
        }
        __syncthreads();
    }
}

extern "C" void kernel_launch(void* const* d_in, const int* in_sizes, int n_in,
                              void* d_out, int out_size, void* d_ws, size_t ws_size,
                              hipStream_t stream)
{
    const float* feats_A = (const float*)d_in[0];
    const float* feats_B = (const float*)d_in[1];
    const float* W_p2c   = (const float*)d_in[2];
    const float* b_p2c   = (const float*)d_in[3];
    const float* W_c2p   = (const float*)d_in[4];
    const float* b_c2p   = (const float*)d_in[5];
    const float* Wself_A = (const float*)d_in[6];
    const float* bself_A = (const float*)d_in[7];
    const float* lnw_A   = (const float*)d_in[8];
    const float* lnb_A   = (const float*)d_in[9];
    const float* Wself_B = (const float*)d_in[10];
    const float* bself_B = (const float*)d_in[11];
    const float* lnw_B   = (const float*)d_in[12];
    const float* lnb_B   = (const float*)d_in[13];
    const float* u_p2c   = (const float*)d_in[14];
    const float* u_c2p   = (const float*)d_in[15];
    const float* u_featA = (const float*)d_in[16];
    const float* u_featB = (const float*)d_in[17];
    const int* src_p2c = (const int*)d_in[18];
    const int* dst_p2c = (const int*)d_in[19];
    const int* src_c2p = (const int*)d_in[20];
    const int* dst_c2p = (const int*)d_in[21];

    const int N_A = in_sizes[0] / DD;   // 200000
    const int N_B = in_sizes[1] / DD;   // 400000
    const int E1  = in_sizes[14];       // 800000
    const int E2  = in_sizes[15];       // 800000

    const size_t preA_n = (size_t)N_A * DD;   // 25.6M
    const size_t preB_n = (size_t)N_B * DD;   // 51.2M

    float* outA = (float*)d_out;
    float* outB = outA + preA_n;

    const size_t need1 = (preA_n + preB_n + N_A + N_B) * sizeof(float); // ~310MB
    const size_t need2 = (preB_n + N_A + N_B) * sizeof(float);          // ~207MB

    float *pre_A, *pre_B, *deg_A, *deg_B;
    if (ws_size >= need1) {
        pre_A = (float*)d_ws;
        pre_B = pre_A + preA_n;
        deg_A = pre_B + preB_n;
        deg_B = deg_A + N_A;
        hipMemsetAsync(d_ws, 0, need1, stream);
    } else if (ws_size >= need2) {
        // pre_A (f32, 102.4MB) overlays the front of the out_B region (f32, 204.8MB).
        // Safe: table_A consumes pre_A fully before table_B writes out_B (stream order).
        pre_A = (float*)((char*)d_out + preA_n * sizeof(float));
        pre_B = (float*)d_ws;
        deg_A = pre_B + preB_n;
        deg_B = deg_A + N_A;
        hipMemsetAsync(d_ws, 0, need2, stream);
        hipMemsetAsync(pre_A, 0, preA_n * sizeof(float), stream);
    } else {
        return; // insufficient workspace: fail visibly without corrupting memory
    }

    dim3 sblk(256), sgrd(2048);
    // PARENT_TO_CHILD: A -> B
    scatter_kernel<<<sgrd, sblk, 0, stream>>>(feats_A, src_p2c, dst_p2c, u_p2c, pre_B, deg_B, E1);
    // CHILD_TO_PARENT: B -> A
    scatter_kernel<<<sgrd, sblk, 0, stream>>>(feats_B, src_c2p, dst_c2p, u_c2p, pre_A, deg_A, E2);

    dim3 tblk(512);
    int itersA = N_A / 32, itersB = N_B / 32;
    dim3 tgrdA((unsigned)(itersA < 2048 ? itersA : 2048));
    dim3 tgrdB((unsigned)(itersB < 2048 ? itersB : 2048));
    table_kernel<<<tgrdA, tblk, 0, stream>>>(feats_A, pre_A, deg_A,
                                             Wself_A, bself_A, W_c2p, b_c2p,
                                             lnw_A, lnb_A, u_featA, outA, N_A);
    table_kernel<<<tgrdB, tblk, 0, stream>>>(feats_B, pre_B, deg_B,
                                             Wself_B, bself_B, W_p2c, b_p2c,
                                             lnw_B, lnb_B, u_featB, outB, N_B);
}